// Round 3
// baseline (1919.874 us; speedup 1.0000x reference)
//
#include <hip/hip_runtime.h>
#include <stdint.h>

// ============================================================================
// StochasticLSTMPredictor VRNN scan. B=256,T=512,I=128,H=256,L=64,HPR=50
// R6: main loop is LDS-instruction-throughput bound (216 ds_read_b128/t/CU
// ~= 2600cyc ~= the 50% non-VALU time). Two coupled changes:
//  (1) Offload ALL non-recurrent work (p_mu/p_lv MLPs, Wo+sigmoid x_hat) to
//      a post-pass kernel vrnn_post. Main parks h_t (raw fp16, exact) into
//      the pmu|plv|xhat output slots; vrnn_post reads h + qmu/qlv + noise,
//      recomputes z, computes p/x_hat and overwrites the slots.
//  (2) With P1's pinned weights down to 76 u32, hoist P2-q and P4 weights
//      into registers too (108 pinned total); s_w2 LDS deleted entirely.
// Main per-t LDS instrs: 216 -> ~110; VALU work -40%. Prep/ws unchanged.
// ============================================================================

typedef _Float16 f16x2 __attribute__((ext_vector_type(2)));

__device__ __forceinline__ float bf2f(uint16_t u) {
  union { uint32_t u; float f; } c; c.u = ((uint32_t)u) << 16; return c.f;
}
__device__ __forceinline__ uint16_t f2bf(float f) {
  union { float f; uint32_t u; } c; c.f = f;
  uint32_t u = c.u;
  uint32_t r = (u + 0x7FFFu + ((u >> 16) & 1u)) >> 16;
  return (uint16_t)r;
}
__device__ __forceinline__ uint32_t packh2(float a, float b) {
  union { f16x2 h; uint32_t u; } c;
  c.h.x = (_Float16)a; c.h.y = (_Float16)b; return c.u;
}
__device__ __forceinline__ float fdot2(uint32_t a, uint32_t b, float c) {
  union { uint32_t u; f16x2 h; } ua, ub; ua.u = a; ub.u = b;
#if __has_builtin(__builtin_amdgcn_fdot2)
  return __builtin_amdgcn_fdot2(ua.h, ub.h, c, false);
#else
  return c + (float)ua.h.x * (float)ub.h.x + (float)ua.h.y * (float)ub.h.y;
#endif
}

// keep a value in a VGPR; forbids load-sinking/remat of its producer
__device__ __forceinline__ void pin(uint32_t& x) { asm volatile("" : "+v"(x)); }

// ---- DPP butterfly reduction (VALU pipe, no LDS) ----
template <int CTRL>
__device__ __forceinline__ float dpp_mov(float x) {
#if __has_builtin(__builtin_amdgcn_update_dpp)
  union { float f; int i; } a, b;
  a.f = x;
  b.i = __builtin_amdgcn_update_dpp(0, a.i, CTRL, 0xF, 0xF, true);
  return b.f;
#else
  return __shfl_xor(x, (CTRL == 0xB1) ? 1 : (CTRL == 0x4E) ? 2 : 4);
#endif
}
__device__ __forceinline__ float red2(float x) {           // sum over lane pairs
  return x + dpp_mov<0xB1>(x);
}
__device__ __forceinline__ float red4(float x) {           // sum over quads
  x += dpp_mov<0xB1>(x); x += dpp_mov<0x4E>(x); return x;
}
__device__ __forceinline__ float red8(float x) {           // sum over 8 lanes
  x += dpp_mov<0xB1>(x); x += dpp_mov<0x4E>(x); x += dpp_mov<0x141>(x); return x;
}

// LDS-only barrier: no vmcnt(0) drain (global stores/prefetches stay in flight)
__device__ __forceinline__ void barrier_lds() {
  asm volatile("s_waitcnt lgkmcnt(0)\n\ts_barrier" ::: "memory");
}

// dtype sniff (harness test is bf16; reference f32 — support both)
__device__ __forceinline__ int sniff_bf16(const uint32_t* xw) {
  int cnt = 0;
#pragma unroll
  for (int i = 0; i < 64; ++i) {
    uint32_t e = (xw[i] >> 7) & 0xFFu;
    cnt += (e >= 0x70u && e <= 0x7Fu) ? 1 : 0;
  }
  return cnt >= 32;
}
__device__ __forceinline__ float loadIn(const void* p, size_t i, int isbf) {
  return isbf ? bf2f(((const uint16_t*)p)[i]) : ((const float*)p)[i];
}
__device__ __forceinline__ void storeOut(void* p, size_t i, float v, int isbf) {
  if (isbf) ((uint16_t*)p)[i] = f2bf(v);
  else      ((float*)p)[i] = v;
}
// park h as raw fp16 bits (exact round-trip) in bf16 mode, f32 otherwise
__device__ __forceinline__ void parkStore(void* p, size_t i, float v, int isbf) {
  if (isbf) {
    union { _Float16 h; uint16_t u; } c; c.h = (_Float16)v;
    ((uint16_t*)p)[i] = c.u;
  } else ((float*)p)[i] = v;
}
__device__ __forceinline__ _Float16 parkLoadH(const void* p, size_t i, int isbf) {
  if (isbf) {
    union { uint16_t u; _Float16 h; } c; c.u = ((const uint16_t*)p)[i];
    return c.h;
  }
  return (_Float16)((const float*)p)[i];
}

// ws layout (uint32 units):
// [0, 75776)          : 148 pairs x 512 threads, SoA [pair][tid], f16x2
// [75776, 94208)      : W2 image: qm2@0 ql2@2304 pm2@4608 pl2@6912 (64 rows x
//                       stride36), wh2@9216 (256 rows x stride36)
// [94208, 95168)      : biases f32: [0:320) L1 5x64 | [320:576) L2 4x64
//                       | [576:832) bh2 | [832:960) bo
#define WS_W2   75776
#define WS_BIAS 94208
#define N_JOBS  95168

#define OFF_PMU 16777216u
#define OFF_PLV 25165824u
#define OFF_QMU 33554432u
#define OFF_QLV 41943040u

struct PrepArgs {
  const void* W[11]; // qm1 ql1 pm1 pl1 h1 wo qm2 ql2 pm2 pl2 h2
  const void* B[11]; // bqm1 bql1 bpm1 bpl1 bh1 bqm2 bql2 bpm2 bpl2 bh2 bo
  const uint32_t* xw;
};

__global__ void vrnn_prep(PrepArgs a, uint32_t* __restrict__ ws) {
  const int isbf = sniff_bf16(a.xw);
  int j = blockIdx.x * 256 + threadIdx.x;
  if (j < 75776) {
    int p = j >> 9, tid = j & 511;
    int t8 = tid >> 3, c8 = tid & 7;
    const void* W; int row, k, K; bool valid;
    if (p < 24)       { W = a.W[0]; row = t8; k = c8*48 + p*2;        K = 384; valid = row < 50; }
    else if (p < 48)  { W = a.W[1]; row = t8; k = c8*48 + (p-24)*2;   K = 384; valid = row < 50; }
    else if (p < 64)  { W = a.W[2]; row = t8; k = c8*32 + (p-48)*2;   K = 256; valid = row < 50; }
    else if (p < 80)  { W = a.W[3]; row = t8; k = c8*32 + (p-64)*2;   K = 256; valid = row < 50; }
    else if (p < 104) { W = a.W[4]; row = t8; k = c8*48 + (p-80)*2;   K = 448; valid = row < 50; }
    else if (p < 108) { W = a.W[4]; row = t8; k = 384 + c8*8 + (p-104)*2; K = 448; valid = row < 50; }
    else if (p < 124) { W = a.W[5]; row = t8;      k = c8*32 + (p-108)*2;     K = 320; valid = true; }
    else if (p < 128) { W = a.W[5]; row = t8;      k = 256 + c8*8 + (p-124)*2; K = 320; valid = true; }
    else if (p < 144) { W = a.W[5]; row = 64 + t8; k = c8*32 + (p-128)*2;     K = 320; valid = true; }
    else              { W = a.W[5]; row = 64 + t8; k = 256 + c8*8 + (p-144)*2; K = 320; valid = true; }
    float f0 = valid ? loadIn(W, (size_t)row * K + k, isbf)     : 0.f;
    float f1 = valid ? loadIn(W, (size_t)row * K + k + 1, isbf) : 0.f;
    ws[j] = packh2(f0, f1);
  } else if (j < WS_BIAS) {
    int q = j - WS_W2;
    const void* W; int r, kp;
    if (q < 9216) { int m = q / 2304, rem = q % 2304; r = rem / 36; kp = rem % 36; W = a.W[6 + m]; }
    else          { int rem = q - 9216;               r = rem / 36; kp = rem % 36; W = a.W[10]; }
    uint32_t v = 0;
    if (kp < 25) v = packh2(loadIn(W, r * 50 + kp * 2, isbf),
                            loadIn(W, r * 50 + kp * 2 + 1, isbf));
    ws[j] = v;
  } else if (j < N_JOBS) {
    int q = j - WS_BIAS; float v = 0.f;
    if (q < 320)      { int m = q >> 6, i = q & 63; if (i < 50) v = loadIn(a.B[m], i, isbf); }
    else if (q < 576) { int m = (q - 320) >> 6;     v = loadIn(a.B[5 + m], q & 63, isbf); }
    else if (q < 832) { v = loadIn(a.B[9],  q - 576, isbf); }
    else              { v = loadIn(a.B[10], q - 832, isbf); }
    ((float*)ws)[j] = v;
  }
}

// ============================= main scan ====================================
__global__ __launch_bounds__(512)
__attribute__((amdgpu_waves_per_eu(2, 2)))
void vrnn_main(
    const void* __restrict__ x, const void* __restrict__ hidden,
    const void* __restrict__ noise, const uint32_t* __restrict__ ws,
    void* __restrict__ out)
{
  __shared__ float s_bias[960];
  __shared__ __align__(16) _Float16 s_v[448];    // [x(128)|h(256)|z(64)]
  __shared__ __align__(16) uint32_t s_actu[180]; // stride-36 arrays: qm@0 ql@36 acth@144
  _Float16* s_act = (_Float16*)s_actu;

  const int tid = threadIdx.x;
  const int b = blockIdx.x;
  const int isbf = sniff_bf16((const uint32_t*)x);

  const int row8 = tid >> 3, c8 = tid & 7;
  const int i2 = tid >> 2, c4 = tid & 3;          // P2: q dot id, lane-in-dot
  const int rh = tid >> 1, ch = tid & 1;          // P4

  // ---- register-resident weights (pinned; 108 u32 total) ----
  uint32_t wqm1[24], wql1[24], wh1a[24], wh1z[4];
#pragma unroll
  for (int i = 0; i < 24; ++i) { wqm1[i] = ws[(0   + i) * 512 + tid]; pin(wqm1[i]); }
#pragma unroll
  for (int i = 0; i < 24; ++i) { wql1[i] = ws[(24  + i) * 512 + tid]; pin(wql1[i]); }
#pragma unroll
  for (int i = 0; i < 24; ++i) { wh1a[i] = ws[(80  + i) * 512 + tid]; pin(wh1a[i]); }
#pragma unroll
  for (int i = 0; i < 4;  ++i) { wh1z[i] = ws[(104 + i) * 512 + tid]; pin(wh1z[i]); }

  const int r2 = i2 & 63;                          // q row (threads >=256 load dummies)
  uint32_t q2wm[8], q2wl[8];
#pragma unroll
  for (int j = 0; j < 8; ++j) { q2wm[j] = ws[WS_W2 + r2*36 + c4*8 + j];        pin(q2wm[j]); }
#pragma unroll
  for (int j = 0; j < 8; ++j) { q2wl[j] = ws[WS_W2 + 2304 + r2*36 + c4*8 + j]; pin(q2wl[j]); }
  uint32_t p4w[16];
#pragma unroll
  for (int j = 0; j < 16; ++j) { p4w[j] = ws[WS_W2 + 9216 + rh*36 + ch*16 + j]; pin(p4w[j]); }

  {
    const float* wsf = (const float*)(ws + WS_BIAS);
    for (int i = tid; i < 960; i += 512) s_bias[i] = wsf[i];
  }

  if (tid < 128)      s_v[tid] = (_Float16)loadIn(x, (size_t)b * 65536 + tid, isbf);
  else if (tid < 384) s_v[tid] = (_Float16)loadIn(hidden, (size_t)b * 256 + (tid - 128), isbf);
  else if (tid < 448) s_v[tid] = (_Float16)0.f;

  const uint4* v4 = (const uint4*)s_v;

  float eps_r = 0.f;
  if (c4 == 0 && i2 < 64) eps_r = loadIn(noise, (size_t)b * 32768 + i2, isbf);
  float xnext = 0.f;
  float hprev = 0.f;                               // h entering current step (ch==0 lanes)
  if (ch == 0) hprev = loadIn(hidden, (size_t)b * 256 + rh, isbf);

  __syncthreads();

#pragma unroll 1
  for (int t = 0; t < 512; ++t) {
    const size_t bt = (size_t)b * 512 + t;
    // prefetch x_{t+1} (committed to s_v in P4)
    if (tid >= 384) {
      int tn = (t < 511) ? t + 1 : 511;
      xnext = loadIn(x, ((size_t)b * 512 + tn) * 128 + (tid - 384), isbf);
    }
    // park h_t (input state of this step) raw fp16 into pmu|plv|xhat slots
    if (ch == 0) {
      size_t pidx = (rh < 64)  ? OFF_PMU + bt * 64 + rh
                  : (rh < 128) ? OFF_PLV + bt * 64 + (rh - 64)
                               : bt * 128 + (rh - 128);
      parkStore(out, pidx, hprev, isbf);
    }

    // ---- P1: q-path L1 + Wh1 (x,h)-part; 8 lanes/row ----
    float a_qm = 0.f, a_ql = 0.f, a_hx = 0.f;
    {
      const int g = c8 * 6;                        // xh = v[0:384]
#pragma unroll
      for (int i = 0; i < 6; ++i) {
        uint4 q = v4[g + i];
        a_qm = fdot2(wqm1[4*i+0], q.x, a_qm); a_ql = fdot2(wql1[4*i+0], q.x, a_ql); a_hx = fdot2(wh1a[4*i+0], q.x, a_hx);
        a_qm = fdot2(wqm1[4*i+1], q.y, a_qm); a_ql = fdot2(wql1[4*i+1], q.y, a_ql); a_hx = fdot2(wh1a[4*i+1], q.y, a_hx);
        a_qm = fdot2(wqm1[4*i+2], q.z, a_qm); a_ql = fdot2(wql1[4*i+2], q.z, a_ql); a_hx = fdot2(wh1a[4*i+2], q.z, a_hx);
        a_qm = fdot2(wqm1[4*i+3], q.w, a_qm); a_ql = fdot2(wql1[4*i+3], q.w, a_ql); a_hx = fdot2(wh1a[4*i+3], q.w, a_hx);
      }
    }
    a_qm = red8(a_qm); a_ql = red8(a_ql);
    if (c8 == 0) {
      s_act[row8]      = (_Float16)fmaxf(a_qm + s_bias[row8],      0.f);
      s_act[72 + row8] = (_Float16)fmaxf(a_ql + s_bias[64 + row8], 0.f);
    }
    barrier_lds();

    // ---- P2: q L2 (mu & lv per row) + z; waves 0-3 only ----
    if (tid < 256) {
      uint4 am0 = *(const uint4*)(s_actu + c4*8),      am1 = *(const uint4*)(s_actu + c4*8 + 4);
      uint4 al0 = *(const uint4*)(s_actu + 36 + c4*8), al1 = *(const uint4*)(s_actu + 36 + c4*8 + 4);
      float mu0 = 0.f, mu1 = 0.f, lv0 = 0.f, lv1 = 0.f;
      mu0 = fdot2(q2wm[0], am0.x, mu0); lv0 = fdot2(q2wl[0], al0.x, lv0);
      mu1 = fdot2(q2wm[4], am1.x, mu1); lv1 = fdot2(q2wl[4], al1.x, lv1);
      mu0 = fdot2(q2wm[1], am0.y, mu0); lv0 = fdot2(q2wl[1], al0.y, lv0);
      mu1 = fdot2(q2wm[5], am1.y, mu1); lv1 = fdot2(q2wl[5], al1.y, lv1);
      mu0 = fdot2(q2wm[2], am0.z, mu0); lv0 = fdot2(q2wl[2], al0.z, lv0);
      mu1 = fdot2(q2wm[6], am1.z, mu1); lv1 = fdot2(q2wl[6], al1.z, lv1);
      mu0 = fdot2(q2wm[3], am0.w, mu0); lv0 = fdot2(q2wl[3], al0.w, lv0);
      mu1 = fdot2(q2wm[7], am1.w, mu1); lv1 = fdot2(q2wl[7], al1.w, lv1);
      float mu = red4(mu0 + mu1);
      float lv = red4(lv0 + lv1);
      if (c4 == 0) {
        mu += s_bias[320 + r2];
        lv += s_bias[384 + r2];
        storeOut(out, OFF_QMU + bt * 64 + r2, mu, isbf);
        storeOut(out, OFF_QLV + bt * 64 + r2, lv, isbf);
        float z = mu + __expf(0.5f * lv) * eps_r;
        s_v[384 + r2] = (_Float16)z;
        int tn = (t < 511) ? t + 1 : 511;
        eps_r = loadIn(noise, ((size_t)b * 512 + tn) * 64 + r2, isbf);
      }
    }
    barrier_lds();

    // ---- P3: Wh1 z-part completion -> act_h ----
    {
      uint4 qz = v4[48 + c8];                      // z = v[384:448)
      float ah = a_hx;
      ah = fdot2(wh1z[0], qz.x, ah);
      ah = fdot2(wh1z[1], qz.y, ah);
      ah = fdot2(wh1z[2], qz.z, ah);
      ah = fdot2(wh1z[3], qz.w, ah);
      ah = red8(ah);
      if (c8 == 0)
        s_act[288 + row8] = (_Float16)fmaxf(ah + s_bias[256 + row8], 0.f);
    }
    barrier_lds();

    // ---- P4: h-update (2 lanes/row), weights in regs; commit x_{t+1} ----
    {
      const uint32_t* ap = s_actu + 144 + ch * 16;
      uint4 a0 = *(const uint4*)ap,        a1 = *(const uint4*)(ap + 4);
      uint4 a2 = *(const uint4*)(ap + 8),  a3 = *(const uint4*)(ap + 12);
      float h0 = 0.f, h1 = 0.f;
      h0 = fdot2(p4w[0],  a0.x, h0); h1 = fdot2(p4w[8],  a2.x, h1);
      h0 = fdot2(p4w[1],  a0.y, h0); h1 = fdot2(p4w[9],  a2.y, h1);
      h0 = fdot2(p4w[2],  a0.z, h0); h1 = fdot2(p4w[10], a2.z, h1);
      h0 = fdot2(p4w[3],  a0.w, h0); h1 = fdot2(p4w[11], a2.w, h1);
      h0 = fdot2(p4w[4],  a1.x, h0); h1 = fdot2(p4w[12], a3.x, h1);
      h0 = fdot2(p4w[5],  a1.y, h0); h1 = fdot2(p4w[13], a3.y, h1);
      h0 = fdot2(p4w[6],  a1.z, h0); h1 = fdot2(p4w[14], a3.z, h1);
      h0 = fdot2(p4w[7],  a1.w, h0); h1 = fdot2(p4w[15], a3.w, h1);
      float hh = red2(h0 + h1);
      if (ch == 0) {
        float hv = hh + s_bias[576 + rh];
        s_v[128 + rh] = (_Float16)hv;
        hprev = hv;
      }
    }
    if (tid >= 384) s_v[tid - 384] = (_Float16)xnext;
    barrier_lds();
  }
}

// ====================== post-pass: p-path + x_hat ===========================
// Fully parallel over (b,t). Reads parked h (raw fp16) + qmu/qlv + noise,
// recomputes z, overwrites pmu/plv/xhat slots.
__global__ __launch_bounds__(512)
__attribute__((amdgpu_waves_per_eu(2, 2)))
void vrnn_post(
    const void* __restrict__ x, const void* __restrict__ noise,
    const uint32_t* __restrict__ ws, void* __restrict__ out)
{
  __shared__ float s_bias[960];
  __shared__ __align__(16) _Float16 s_v[448];    // [unused(128)|h(256)|z(64)]
  __shared__ __align__(16) uint32_t s_actu[180]; // pm@72 pl@108 (u32 offsets)
  _Float16* s_act = (_Float16*)s_actu;

  const int tid = threadIdx.x;
  const int isbf = sniff_bf16((const uint32_t*)x);

  const int row8 = tid >> 3, c8 = tid & 7;
  const int c4 = tid & 3;
  const int gid = tid >> 2;                       // P2': 0-63 pmu, 64-127 plv
  const int mp = gid >> 6, rr = gid & 63;

  // ---- register-resident weights (pinned; 80 u32) ----
  uint32_t wpm1[16], wpl1[16], wo0h[16], wo0z[4], wo1h[16], wo1z[4];
#pragma unroll
  for (int i = 0; i < 16; ++i) { wpm1[i] = ws[(48  + i) * 512 + tid]; pin(wpm1[i]); }
#pragma unroll
  for (int i = 0; i < 16; ++i) { wpl1[i] = ws[(64  + i) * 512 + tid]; pin(wpl1[i]); }
#pragma unroll
  for (int i = 0; i < 16; ++i) { wo0h[i] = ws[(108 + i) * 512 + tid]; pin(wo0h[i]); }
#pragma unroll
  for (int i = 0; i < 4;  ++i) { wo0z[i] = ws[(124 + i) * 512 + tid]; pin(wo0z[i]); }
#pragma unroll
  for (int i = 0; i < 16; ++i) { wo1h[i] = ws[(128 + i) * 512 + tid]; pin(wo1h[i]); }
#pragma unroll
  for (int i = 0; i < 4;  ++i) { wo1z[i] = ws[(144 + i) * 512 + tid]; pin(wo1z[i]); }
  uint32_t pw[8];
#pragma unroll
  for (int j = 0; j < 8; ++j) { pw[j] = ws[WS_W2 + (mp ? 6912 : 4608) + rr*36 + c4*8 + j]; pin(pw[j]); }

  {
    const float* wsf = (const float*)(ws + WS_BIAS);
    for (int i = tid; i < 960; i += 512) s_bias[i] = wsf[i];
  }
  __syncthreads();

  const uint4* v4 = (const uint4*)s_v;

#pragma unroll 1
  for (int it = 0; it < 64; ++it) {
    const size_t g = (size_t)blockIdx.x * 64 + it;   // bt index

    // ---- stage: h from park slots; z recomputed from qmu/qlv/noise ----
    if (tid < 256) {
      int r = tid;
      size_t pidx = (r < 64)  ? OFF_PMU + g * 64 + r
                  : (r < 128) ? OFF_PLV + g * 64 + (r - 64)
                              : g * 128 + (r - 128);
      s_v[128 + r] = parkLoadH(out, pidx, isbf);
    } else if (tid < 320) {
      int r = tid - 256;
      float mu  = loadIn(out, OFF_QMU + g * 64 + r, isbf);
      float lv  = loadIn(out, OFF_QLV + g * 64 + r, isbf);
      float eps = loadIn(noise, g * 64 + r, isbf);
      s_v[384 + r] = (_Float16)(mu + __expf(0.5f * lv) * eps);
    }
    barrier_lds();

    // ---- P1': pm/pl L1 dots + full Wo dots; 8 lanes/row ----
    float a_pm = 0.f, a_pl = 0.f, a_o0 = 0.f, a_o1 = 0.f;
    {
      const int gg = 16 + c8 * 4;                  // h = v[128:384]
#pragma unroll
      for (int i = 0; i < 4; ++i) {
        uint4 q = v4[gg + i];
        a_pm = fdot2(wpm1[4*i+0], q.x, a_pm); a_pl = fdot2(wpl1[4*i+0], q.x, a_pl);
        a_o0 = fdot2(wo0h[4*i+0], q.x, a_o0); a_o1 = fdot2(wo1h[4*i+0], q.x, a_o1);
        a_pm = fdot2(wpm1[4*i+1], q.y, a_pm); a_pl = fdot2(wpl1[4*i+1], q.y, a_pl);
        a_o0 = fdot2(wo0h[4*i+1], q.y, a_o0); a_o1 = fdot2(wo1h[4*i+1], q.y, a_o1);
        a_pm = fdot2(wpm1[4*i+2], q.z, a_pm); a_pl = fdot2(wpl1[4*i+2], q.z, a_pl);
        a_o0 = fdot2(wo0h[4*i+2], q.z, a_o0); a_o1 = fdot2(wo1h[4*i+2], q.z, a_o1);
        a_pm = fdot2(wpm1[4*i+3], q.w, a_pm); a_pl = fdot2(wpl1[4*i+3], q.w, a_pl);
        a_o0 = fdot2(wo0h[4*i+3], q.w, a_o0); a_o1 = fdot2(wo1h[4*i+3], q.w, a_o1);
      }
      uint4 qz = v4[48 + c8];                      // z part of Wo
      a_o0 = fdot2(wo0z[0], qz.x, a_o0); a_o1 = fdot2(wo1z[0], qz.x, a_o1);
      a_o0 = fdot2(wo0z[1], qz.y, a_o0); a_o1 = fdot2(wo1z[1], qz.y, a_o1);
      a_o0 = fdot2(wo0z[2], qz.z, a_o0); a_o1 = fdot2(wo1z[2], qz.z, a_o1);
      a_o0 = fdot2(wo0z[3], qz.w, a_o0); a_o1 = fdot2(wo1z[3], qz.w, a_o1);
    }
    a_pm = red8(a_pm); a_pl = red8(a_pl); a_o0 = red8(a_o0); a_o1 = red8(a_o1);
    if (c8 == 0) {
      s_act[144 + row8] = (_Float16)fmaxf(a_pm + s_bias[128 + row8], 0.f);
      s_act[216 + row8] = (_Float16)fmaxf(a_pl + s_bias[192 + row8], 0.f);
      float s0 = 1.f / (1.f + __expf(-(a_o0 + s_bias[832 + row8])));
      float s1 = 1.f / (1.f + __expf(-(a_o1 + s_bias[896 + row8])));
      storeOut(out, g * 128 + row8, s0, isbf);
      storeOut(out, g * 128 + 64 + row8, s1, isbf);
    }
    barrier_lds();

    // ---- P2': p L2 (gid<64: pmu row, gid>=64: plv row), 4 lanes/dot ----
    {
      const uint32_t* ab = s_actu + (mp ? 108 : 72) + c4 * 8;
      uint4 a0 = *(const uint4*)ab, a1 = *(const uint4*)(ab + 4);
      float v0 = 0.f, v1 = 0.f;
      v0 = fdot2(pw[0], a0.x, v0); v1 = fdot2(pw[4], a1.x, v1);
      v0 = fdot2(pw[1], a0.y, v0); v1 = fdot2(pw[5], a1.y, v1);
      v0 = fdot2(pw[2], a0.z, v0); v1 = fdot2(pw[6], a1.z, v1);
      v0 = fdot2(pw[3], a0.w, v0); v1 = fdot2(pw[7], a1.w, v1);
      float v = red4(v0 + v1);
      if (c4 == 0) {
        v += s_bias[(mp ? 512 : 448) + rr];
        storeOut(out, (mp ? OFF_PLV : OFF_PMU) + g * 64 + rr, v, isbf);
      }
    }
    barrier_lds();
  }
}

extern "C" void kernel_launch(void* const* d_in, const int* in_sizes, int n_in,
                              void* d_out, int out_size, void* d_ws, size_t ws_size,
                              hipStream_t stream) {
  (void)in_sizes; (void)n_in; (void)out_size; (void)ws_size;
  PrepArgs a;
  a.W[0]  = d_in[11]; // Wqm1 [50,384]
  a.W[1]  = d_in[15]; // Wql1 [50,384]
  a.W[2]  = d_in[3];  // Wpm1 [50,256]
  a.W[3]  = d_in[7];  // Wpl1 [50,256]
  a.W[4]  = d_in[19]; // Wh1  [50,448]
  a.W[5]  = d_in[23]; // Wo   [128,320]
  a.W[6]  = d_in[13]; // Wqm2 [64,50]
  a.W[7]  = d_in[17]; // Wql2 [64,50]
  a.W[8]  = d_in[5];  // Wpm2 [64,50]
  a.W[9]  = d_in[9];  // Wpl2 [64,50]
  a.W[10] = d_in[21]; // Wh2  [256,50]
  a.B[0]  = d_in[12]; // bqm1
  a.B[1]  = d_in[16]; // bql1
  a.B[2]  = d_in[4];  // bpm1
  a.B[3]  = d_in[8];  // bpl1
  a.B[4]  = d_in[20]; // bh1
  a.B[5]  = d_in[14]; // bqm2
  a.B[6]  = d_in[18]; // bql2
  a.B[7]  = d_in[6];  // bpm2
  a.B[8]  = d_in[10]; // bpl2
  a.B[9]  = d_in[22]; // bh2
  a.B[10] = d_in[24]; // bo
  a.xw    = (const uint32_t*)d_in[0];

  uint32_t* ws = (uint32_t*)d_ws;
  vrnn_prep<<<dim3((N_JOBS + 255) / 256), dim3(256), 0, stream>>>(a, ws);
  vrnn_main<<<dim3(256), dim3(512), 0, stream>>>(d_in[0], d_in[1], d_in[2], ws, d_out);
  vrnn_post<<<dim3(2048), dim3(512), 0, stream>>>(d_in[0], d_in[2], ws, d_out);
}

// Round 5
// 1515.483 us; speedup vs baseline: 1.2668x; 1.2668x over previous
//
#include <hip/hip_runtime.h>
#include <stdint.h>

// ============================================================================
// StochasticLSTMPredictor VRNN scan. B=256,T=512,I=128,H=256,L=64,HPR=50
// R8 = R7 resubmit (R7 bench died to an infra/container failure, no counters).
// R7: R6 with vrnn_post fixed (R6's post ran at 900us due to a copied
// amdgpu_waves_per_eu(2,2) attr clamping it to 1 block/CU, plus a fully
// exposed global-load latency chain):
//  - post: __launch_bounds__(512,4) -> VGPR cap 128 (uses ~94), 2 blocks/CU
//  - post: software-prefetch next iteration's h/qmu/qlv/noise into registers
//    right after the commit barrier; barrier_lds never drains vmcnt, so the
//    ~900cyc HBM latency hides under P1'/P2' compute.
// vrnn_main identical to R6 (verified): parks h_t into pmu|plv|xhat slots,
// q-path + Wh1/Wh2 only, weights register-resident, 4 lds-only barriers/t.
// ============================================================================

typedef _Float16 f16x2 __attribute__((ext_vector_type(2)));

__device__ __forceinline__ float bf2f(uint16_t u) {
  union { uint32_t u; float f; } c; c.u = ((uint32_t)u) << 16; return c.f;
}
__device__ __forceinline__ uint16_t f2bf(float f) {
  union { float f; uint32_t u; } c; c.f = f;
  uint32_t u = c.u;
  uint32_t r = (u + 0x7FFFu + ((u >> 16) & 1u)) >> 16;
  return (uint16_t)r;
}
__device__ __forceinline__ uint32_t packh2(float a, float b) {
  union { f16x2 h; uint32_t u; } c;
  c.h.x = (_Float16)a; c.h.y = (_Float16)b; return c.u;
}
__device__ __forceinline__ float fdot2(uint32_t a, uint32_t b, float c) {
  union { uint32_t u; f16x2 h; } ua, ub; ua.u = a; ub.u = b;
#if __has_builtin(__builtin_amdgcn_fdot2)
  return __builtin_amdgcn_fdot2(ua.h, ub.h, c, false);
#else
  return c + (float)ua.h.x * (float)ub.h.x + (float)ua.h.y * (float)ub.h.y;
#endif
}

// keep a value in a VGPR; forbids load-sinking/remat of its producer
__device__ __forceinline__ void pin(uint32_t& x) { asm volatile("" : "+v"(x)); }

// ---- DPP butterfly reduction (VALU pipe, no LDS) ----
template <int CTRL>
__device__ __forceinline__ float dpp_mov(float x) {
#if __has_builtin(__builtin_amdgcn_update_dpp)
  union { float f; int i; } a, b;
  a.f = x;
  b.i = __builtin_amdgcn_update_dpp(0, a.i, CTRL, 0xF, 0xF, true);
  return b.f;
#else
  return __shfl_xor(x, (CTRL == 0xB1) ? 1 : (CTRL == 0x4E) ? 2 : 4);
#endif
}
__device__ __forceinline__ float red2(float x) {           // sum over lane pairs
  return x + dpp_mov<0xB1>(x);
}
__device__ __forceinline__ float red4(float x) {           // sum over quads
  x += dpp_mov<0xB1>(x); x += dpp_mov<0x4E>(x); return x;
}
__device__ __forceinline__ float red8(float x) {           // sum over 8 lanes
  x += dpp_mov<0xB1>(x); x += dpp_mov<0x4E>(x); x += dpp_mov<0x141>(x); return x;
}

// LDS-only barrier: no vmcnt(0) drain (global stores/prefetches stay in flight)
__device__ __forceinline__ void barrier_lds() {
  asm volatile("s_waitcnt lgkmcnt(0)\n\ts_barrier" ::: "memory");
}

// dtype sniff (harness test is bf16; reference f32 — support both)
__device__ __forceinline__ int sniff_bf16(const uint32_t* xw) {
  int cnt = 0;
#pragma unroll
  for (int i = 0; i < 64; ++i) {
    uint32_t e = (xw[i] >> 7) & 0xFFu;
    cnt += (e >= 0x70u && e <= 0x7Fu) ? 1 : 0;
  }
  return cnt >= 32;
}
__device__ __forceinline__ float loadIn(const void* p, size_t i, int isbf) {
  return isbf ? bf2f(((const uint16_t*)p)[i]) : ((const float*)p)[i];
}
__device__ __forceinline__ void storeOut(void* p, size_t i, float v, int isbf) {
  if (isbf) ((uint16_t*)p)[i] = f2bf(v);
  else      ((float*)p)[i] = v;
}
// park h as raw fp16 bits (exact round-trip) in bf16 mode, f32 otherwise
__device__ __forceinline__ void parkStore(void* p, size_t i, float v, int isbf) {
  if (isbf) {
    union { _Float16 h; uint16_t u; } c; c.h = (_Float16)v;
    ((uint16_t*)p)[i] = c.u;
  } else ((float*)p)[i] = v;
}
__device__ __forceinline__ _Float16 parkLoadH(const void* p, size_t i, int isbf) {
  if (isbf) {
    union { uint16_t u; _Float16 h; } c; c.u = ((const uint16_t*)p)[i];
    return c.h;
  }
  return (_Float16)((const float*)p)[i];
}

// ws layout (uint32 units):
// [0, 75776)          : 148 pairs x 512 threads, SoA [pair][tid], f16x2
// [75776, 94208)      : W2 image: qm2@0 ql2@2304 pm2@4608 pl2@6912 (64 rows x
//                       stride36), wh2@9216 (256 rows x stride36)
// [94208, 95168)      : biases f32: [0:320) L1 5x64 | [320:576) L2 4x64
//                       | [576:832) bh2 | [832:960) bo
#define WS_W2   75776
#define WS_BIAS 94208
#define N_JOBS  95168

#define OFF_PMU 16777216u
#define OFF_PLV 25165824u
#define OFF_QMU 33554432u
#define OFF_QLV 41943040u

struct PrepArgs {
  const void* W[11]; // qm1 ql1 pm1 pl1 h1 wo qm2 ql2 pm2 pl2 h2
  const void* B[11]; // bqm1 bql1 bpm1 bpl1 bh1 bqm2 bql2 bpm2 bpl2 bh2 bo
  const uint32_t* xw;
};

__global__ void vrnn_prep(PrepArgs a, uint32_t* __restrict__ ws) {
  const int isbf = sniff_bf16(a.xw);
  int j = blockIdx.x * 256 + threadIdx.x;
  if (j < 75776) {
    int p = j >> 9, tid = j & 511;
    int t8 = tid >> 3, c8 = tid & 7;
    const void* W; int row, k, K; bool valid;
    if (p < 24)       { W = a.W[0]; row = t8; k = c8*48 + p*2;        K = 384; valid = row < 50; }
    else if (p < 48)  { W = a.W[1]; row = t8; k = c8*48 + (p-24)*2;   K = 384; valid = row < 50; }
    else if (p < 64)  { W = a.W[2]; row = t8; k = c8*32 + (p-48)*2;   K = 256; valid = row < 50; }
    else if (p < 80)  { W = a.W[3]; row = t8; k = c8*32 + (p-64)*2;   K = 256; valid = row < 50; }
    else if (p < 104) { W = a.W[4]; row = t8; k = c8*48 + (p-80)*2;   K = 448; valid = row < 50; }
    else if (p < 108) { W = a.W[4]; row = t8; k = 384 + c8*8 + (p-104)*2; K = 448; valid = row < 50; }
    else if (p < 124) { W = a.W[5]; row = t8;      k = c8*32 + (p-108)*2;     K = 320; valid = true; }
    else if (p < 128) { W = a.W[5]; row = t8;      k = 256 + c8*8 + (p-124)*2; K = 320; valid = true; }
    else if (p < 144) { W = a.W[5]; row = 64 + t8; k = c8*32 + (p-128)*2;     K = 320; valid = true; }
    else              { W = a.W[5]; row = 64 + t8; k = 256 + c8*8 + (p-144)*2; K = 320; valid = true; }
    float f0 = valid ? loadIn(W, (size_t)row * K + k, isbf)     : 0.f;
    float f1 = valid ? loadIn(W, (size_t)row * K + k + 1, isbf) : 0.f;
    ws[j] = packh2(f0, f1);
  } else if (j < WS_BIAS) {
    int q = j - WS_W2;
    const void* W; int r, kp;
    if (q < 9216) { int m = q / 2304, rem = q % 2304; r = rem / 36; kp = rem % 36; W = a.W[6 + m]; }
    else          { int rem = q - 9216;               r = rem / 36; kp = rem % 36; W = a.W[10]; }
    uint32_t v = 0;
    if (kp < 25) v = packh2(loadIn(W, r * 50 + kp * 2, isbf),
                            loadIn(W, r * 50 + kp * 2 + 1, isbf));
    ws[j] = v;
  } else if (j < N_JOBS) {
    int q = j - WS_BIAS; float v = 0.f;
    if (q < 320)      { int m = q >> 6, i = q & 63; if (i < 50) v = loadIn(a.B[m], i, isbf); }
    else if (q < 576) { int m = (q - 320) >> 6;     v = loadIn(a.B[5 + m], q & 63, isbf); }
    else if (q < 832) { v = loadIn(a.B[9],  q - 576, isbf); }
    else              { v = loadIn(a.B[10], q - 832, isbf); }
    ((float*)ws)[j] = v;
  }
}

// ============================= main scan ====================================
__global__ __launch_bounds__(512)
__attribute__((amdgpu_waves_per_eu(2, 2)))
void vrnn_main(
    const void* __restrict__ x, const void* __restrict__ hidden,
    const void* __restrict__ noise, const uint32_t* __restrict__ ws,
    void* __restrict__ out)
{
  __shared__ float s_bias[960];
  __shared__ __align__(16) _Float16 s_v[448];    // [x(128)|h(256)|z(64)]
  __shared__ __align__(16) uint32_t s_actu[180]; // stride-36 arrays: qm@0 ql@36 acth@144
  _Float16* s_act = (_Float16*)s_actu;

  const int tid = threadIdx.x;
  const int b = blockIdx.x;
  const int isbf = sniff_bf16((const uint32_t*)x);

  const int row8 = tid >> 3, c8 = tid & 7;
  const int i2 = tid >> 2, c4 = tid & 3;          // P2: q dot id, lane-in-dot
  const int rh = tid >> 1, ch = tid & 1;          // P4

  // ---- register-resident weights (pinned; 108 u32 total) ----
  uint32_t wqm1[24], wql1[24], wh1a[24], wh1z[4];
#pragma unroll
  for (int i = 0; i < 24; ++i) { wqm1[i] = ws[(0   + i) * 512 + tid]; pin(wqm1[i]); }
#pragma unroll
  for (int i = 0; i < 24; ++i) { wql1[i] = ws[(24  + i) * 512 + tid]; pin(wql1[i]); }
#pragma unroll
  for (int i = 0; i < 24; ++i) { wh1a[i] = ws[(80  + i) * 512 + tid]; pin(wh1a[i]); }
#pragma unroll
  for (int i = 0; i < 4;  ++i) { wh1z[i] = ws[(104 + i) * 512 + tid]; pin(wh1z[i]); }

  const int r2 = i2 & 63;                          // q row (threads >=256 load dummies)
  uint32_t q2wm[8], q2wl[8];
#pragma unroll
  for (int j = 0; j < 8; ++j) { q2wm[j] = ws[WS_W2 + r2*36 + c4*8 + j];        pin(q2wm[j]); }
#pragma unroll
  for (int j = 0; j < 8; ++j) { q2wl[j] = ws[WS_W2 + 2304 + r2*36 + c4*8 + j]; pin(q2wl[j]); }
  uint32_t p4w[16];
#pragma unroll
  for (int j = 0; j < 16; ++j) { p4w[j] = ws[WS_W2 + 9216 + rh*36 + ch*16 + j]; pin(p4w[j]); }

  {
    const float* wsf = (const float*)(ws + WS_BIAS);
    for (int i = tid; i < 960; i += 512) s_bias[i] = wsf[i];
  }

  if (tid < 128)      s_v[tid] = (_Float16)loadIn(x, (size_t)b * 65536 + tid, isbf);
  else if (tid < 384) s_v[tid] = (_Float16)loadIn(hidden, (size_t)b * 256 + (tid - 128), isbf);
  else if (tid < 448) s_v[tid] = (_Float16)0.f;

  const uint4* v4 = (const uint4*)s_v;

  float eps_r = 0.f;
  if (c4 == 0 && i2 < 64) eps_r = loadIn(noise, (size_t)b * 32768 + i2, isbf);
  float xnext = 0.f;
  float hprev = 0.f;                               // h entering current step (ch==0 lanes)
  if (ch == 0) hprev = loadIn(hidden, (size_t)b * 256 + rh, isbf);

  __syncthreads();

#pragma unroll 1
  for (int t = 0; t < 512; ++t) {
    const size_t bt = (size_t)b * 512 + t;
    // prefetch x_{t+1} (committed to s_v in P4)
    if (tid >= 384) {
      int tn = (t < 511) ? t + 1 : 511;
      xnext = loadIn(x, ((size_t)b * 512 + tn) * 128 + (tid - 384), isbf);
    }
    // park h_t (input state of this step) raw fp16 into pmu|plv|xhat slots
    if (ch == 0) {
      size_t pidx = (rh < 64)  ? OFF_PMU + bt * 64 + rh
                  : (rh < 128) ? OFF_PLV + bt * 64 + (rh - 64)
                               : bt * 128 + (rh - 128);
      parkStore(out, pidx, hprev, isbf);
    }

    // ---- P1: q-path L1 + Wh1 (x,h)-part; 8 lanes/row ----
    float a_qm = 0.f, a_ql = 0.f, a_hx = 0.f;
    {
      const int g = c8 * 6;                        // xh = v[0:384]
#pragma unroll
      for (int i = 0; i < 6; ++i) {
        uint4 q = v4[g + i];
        a_qm = fdot2(wqm1[4*i+0], q.x, a_qm); a_ql = fdot2(wql1[4*i+0], q.x, a_ql); a_hx = fdot2(wh1a[4*i+0], q.x, a_hx);
        a_qm = fdot2(wqm1[4*i+1], q.y, a_qm); a_ql = fdot2(wql1[4*i+1], q.y, a_ql); a_hx = fdot2(wh1a[4*i+1], q.y, a_hx);
        a_qm = fdot2(wqm1[4*i+2], q.z, a_qm); a_ql = fdot2(wql1[4*i+2], q.z, a_ql); a_hx = fdot2(wh1a[4*i+2], q.z, a_hx);
        a_qm = fdot2(wqm1[4*i+3], q.w, a_qm); a_ql = fdot2(wql1[4*i+3], q.w, a_ql); a_hx = fdot2(wh1a[4*i+3], q.w, a_hx);
      }
    }
    a_qm = red8(a_qm); a_ql = red8(a_ql);
    if (c8 == 0) {
      s_act[row8]      = (_Float16)fmaxf(a_qm + s_bias[row8],      0.f);
      s_act[72 + row8] = (_Float16)fmaxf(a_ql + s_bias[64 + row8], 0.f);
    }
    barrier_lds();

    // ---- P2: q L2 (mu & lv per row) + z; waves 0-3 only ----
    if (tid < 256) {
      uint4 am0 = *(const uint4*)(s_actu + c4*8),      am1 = *(const uint4*)(s_actu + c4*8 + 4);
      uint4 al0 = *(const uint4*)(s_actu + 36 + c4*8), al1 = *(const uint4*)(s_actu + 36 + c4*8 + 4);
      float mu0 = 0.f, mu1 = 0.f, lv0 = 0.f, lv1 = 0.f;
      mu0 = fdot2(q2wm[0], am0.x, mu0); lv0 = fdot2(q2wl[0], al0.x, lv0);
      mu1 = fdot2(q2wm[4], am1.x, mu1); lv1 = fdot2(q2wl[4], al1.x, lv1);
      mu0 = fdot2(q2wm[1], am0.y, mu0); lv0 = fdot2(q2wl[1], al0.y, lv0);
      mu1 = fdot2(q2wm[5], am1.y, mu1); lv1 = fdot2(q2wl[5], al1.y, lv1);
      mu0 = fdot2(q2wm[2], am0.z, mu0); lv0 = fdot2(q2wl[2], al0.z, lv0);
      mu1 = fdot2(q2wm[6], am1.z, mu1); lv1 = fdot2(q2wl[6], al1.z, lv1);
      mu0 = fdot2(q2wm[3], am0.w, mu0); lv0 = fdot2(q2wl[3], al0.w, lv0);
      mu1 = fdot2(q2wm[7], am1.w, mu1); lv1 = fdot2(q2wl[7], al1.w, lv1);
      float mu = red4(mu0 + mu1);
      float lv = red4(lv0 + lv1);
      if (c4 == 0) {
        mu += s_bias[320 + r2];
        lv += s_bias[384 + r2];
        storeOut(out, OFF_QMU + bt * 64 + r2, mu, isbf);
        storeOut(out, OFF_QLV + bt * 64 + r2, lv, isbf);
        float z = mu + __expf(0.5f * lv) * eps_r;
        s_v[384 + r2] = (_Float16)z;
        int tn = (t < 511) ? t + 1 : 511;
        eps_r = loadIn(noise, ((size_t)b * 512 + tn) * 64 + r2, isbf);
      }
    }
    barrier_lds();

    // ---- P3: Wh1 z-part completion -> act_h ----
    {
      uint4 qz = v4[48 + c8];                      // z = v[384:448)
      float ah = a_hx;
      ah = fdot2(wh1z[0], qz.x, ah);
      ah = fdot2(wh1z[1], qz.y, ah);
      ah = fdot2(wh1z[2], qz.z, ah);
      ah = fdot2(wh1z[3], qz.w, ah);
      ah = red8(ah);
      if (c8 == 0)
        s_act[288 + row8] = (_Float16)fmaxf(ah + s_bias[256 + row8], 0.f);
    }
    barrier_lds();

    // ---- P4: h-update (2 lanes/row), weights in regs; commit x_{t+1} ----
    {
      const uint32_t* ap = s_actu + 144 + ch * 16;
      uint4 a0 = *(const uint4*)ap,        a1 = *(const uint4*)(ap + 4);
      uint4 a2 = *(const uint4*)(ap + 8),  a3 = *(const uint4*)(ap + 12);
      float h0 = 0.f, h1 = 0.f;
      h0 = fdot2(p4w[0],  a0.x, h0); h1 = fdot2(p4w[8],  a2.x, h1);
      h0 = fdot2(p4w[1],  a0.y, h0); h1 = fdot2(p4w[9],  a2.y, h1);
      h0 = fdot2(p4w[2],  a0.z, h0); h1 = fdot2(p4w[10], a2.z, h1);
      h0 = fdot2(p4w[3],  a0.w, h0); h1 = fdot2(p4w[11], a2.w, h1);
      h0 = fdot2(p4w[4],  a1.x, h0); h1 = fdot2(p4w[12], a3.x, h1);
      h0 = fdot2(p4w[5],  a1.y, h0); h1 = fdot2(p4w[13], a3.y, h1);
      h0 = fdot2(p4w[6],  a1.z, h0); h1 = fdot2(p4w[14], a3.z, h1);
      h0 = fdot2(p4w[7],  a1.w, h0); h1 = fdot2(p4w[15], a3.w, h1);
      float hh = red2(h0 + h1);
      if (ch == 0) {
        float hv = hh + s_bias[576 + rh];
        s_v[128 + rh] = (_Float16)hv;
        hprev = hv;
      }
    }
    if (tid >= 384) s_v[tid - 384] = (_Float16)xnext;
    barrier_lds();
  }
}

// ====================== post-pass: p-path + x_hat ===========================
// Fully parallel over (b,t). Reads parked h (raw fp16) + qmu/qlv + noise,
// recomputes z, overwrites pmu/plv/xhat slots. 2 blocks/CU; next-iteration
// staging data prefetched into registers and committed at loop top, so the
// HBM latency hides under the previous iteration's compute.
__global__ __launch_bounds__(512, 4)
void vrnn_post(
    const void* __restrict__ x, const void* __restrict__ noise,
    const uint32_t* __restrict__ ws, void* __restrict__ out)
{
  __shared__ float s_bias[960];
  __shared__ __align__(16) _Float16 s_v[448];    // [unused(128)|h(256)|z(64)]
  __shared__ __align__(16) uint32_t s_actu[180]; // pm@72 pl@108 (u32 offsets)
  _Float16* s_act = (_Float16*)s_actu;

  const int tid = threadIdx.x;
  const int isbf = sniff_bf16((const uint32_t*)x);

  const int row8 = tid >> 3, c8 = tid & 7;
  const int c4 = tid & 3;
  const int gid = tid >> 2;                       // P2': 0-63 pmu, 64-127 plv
  const int mp = gid >> 6, rr = gid & 63;

  // ---- register-resident weights (pinned; 80 u32) ----
  uint32_t wpm1[16], wpl1[16], wo0h[16], wo0z[4], wo1h[16], wo1z[4];
#pragma unroll
  for (int i = 0; i < 16; ++i) { wpm1[i] = ws[(48  + i) * 512 + tid]; pin(wpm1[i]); }
#pragma unroll
  for (int i = 0; i < 16; ++i) { wpl1[i] = ws[(64  + i) * 512 + tid]; pin(wpl1[i]); }
#pragma unroll
  for (int i = 0; i < 16; ++i) { wo0h[i] = ws[(108 + i) * 512 + tid]; pin(wo0h[i]); }
#pragma unroll
  for (int i = 0; i < 4;  ++i) { wo0z[i] = ws[(124 + i) * 512 + tid]; pin(wo0z[i]); }
#pragma unroll
  for (int i = 0; i < 16; ++i) { wo1h[i] = ws[(128 + i) * 512 + tid]; pin(wo1h[i]); }
#pragma unroll
  for (int i = 0; i < 4;  ++i) { wo1z[i] = ws[(144 + i) * 512 + tid]; pin(wo1z[i]); }
  uint32_t pw[8];
#pragma unroll
  for (int j = 0; j < 8; ++j) { pw[j] = ws[WS_W2 + (mp ? 6912 : 4608) + rr*36 + c4*8 + j]; pin(pw[j]); }

  {
    const float* wsf = (const float*)(ws + WS_BIAS);
    for (int i = tid; i < 960; i += 512) s_bias[i] = wsf[i];
  }
  __syncthreads();

  const uint4* v4 = (const uint4*)s_v;

  // ---- prefetch iteration 0 staging into registers ----
  _Float16 hreg = (_Float16)0.f;
  float mu_r = 0.f, lv_r = 0.f, eps_p = 0.f;
  {
    const size_t g0 = (size_t)blockIdx.x * 64;
    if (tid < 256) {
      size_t pidx = (tid < 64)  ? OFF_PMU + g0 * 64 + tid
                  : (tid < 128) ? OFF_PLV + g0 * 64 + (tid - 64)
                                : g0 * 128 + (tid - 128);
      hreg = parkLoadH(out, pidx, isbf);
    } else if (tid < 320) {
      int r = tid - 256;
      mu_r  = loadIn(out, OFF_QMU + g0 * 64 + r, isbf);
      lv_r  = loadIn(out, OFF_QLV + g0 * 64 + r, isbf);
      eps_p = loadIn(noise, g0 * 64 + r, isbf);
    }
  }

#pragma unroll 1
  for (int it = 0; it < 64; ++it) {
    const size_t g = (size_t)blockIdx.x * 64 + it;   // bt index

    // ---- commit prefetched staging to LDS ----
    if (tid < 256)      s_v[128 + tid] = hreg;
    else if (tid < 320) s_v[384 + (tid - 256)] =
        (_Float16)(mu_r + __expf(0.5f * lv_r) * eps_p);
    barrier_lds();

    // ---- issue prefetch for it+1 (hides under P1'/P2' compute) ----
    {
      const size_t gn = (size_t)blockIdx.x * 64 + ((it < 63) ? it + 1 : 63);
      if (tid < 256) {
        size_t pidx = (tid < 64)  ? OFF_PMU + gn * 64 + tid
                    : (tid < 128) ? OFF_PLV + gn * 64 + (tid - 64)
                                  : gn * 128 + (tid - 128);
        hreg = parkLoadH(out, pidx, isbf);
      } else if (tid < 320) {
        int r = tid - 256;
        mu_r  = loadIn(out, OFF_QMU + gn * 64 + r, isbf);
        lv_r  = loadIn(out, OFF_QLV + gn * 64 + r, isbf);
        eps_p = loadIn(noise, gn * 64 + r, isbf);
      }
    }

    // ---- P1': pm/pl L1 dots + full Wo dots; 8 lanes/row ----
    float a_pm = 0.f, a_pl = 0.f, a_o0 = 0.f, a_o1 = 0.f;
    {
      const int gg = 16 + c8 * 4;                  // h = v[128:384]
#pragma unroll
      for (int i = 0; i < 4; ++i) {
        uint4 q = v4[gg + i];
        a_pm = fdot2(wpm1[4*i+0], q.x, a_pm); a_pl = fdot2(wpl1[4*i+0], q.x, a_pl);
        a_o0 = fdot2(wo0h[4*i+0], q.x, a_o0); a_o1 = fdot2(wo1h[4*i+0], q.x, a_o1);
        a_pm = fdot2(wpm1[4*i+1], q.y, a_pm); a_pl = fdot2(wpl1[4*i+1], q.y, a_pl);
        a_o0 = fdot2(wo0h[4*i+1], q.y, a_o0); a_o1 = fdot2(wo1h[4*i+1], q.y, a_o1);
        a_pm = fdot2(wpm1[4*i+2], q.z, a_pm); a_pl = fdot2(wpl1[4*i+2], q.z, a_pl);
        a_o0 = fdot2(wo0h[4*i+2], q.z, a_o0); a_o1 = fdot2(wo1h[4*i+2], q.z, a_o1);
        a_pm = fdot2(wpm1[4*i+3], q.w, a_pm); a_pl = fdot2(wpl1[4*i+3], q.w, a_pl);
        a_o0 = fdot2(wo0h[4*i+3], q.w, a_o0); a_o1 = fdot2(wo1h[4*i+3], q.w, a_o1);
      }
      uint4 qz = v4[48 + c8];                      // z part of Wo
      a_o0 = fdot2(wo0z[0], qz.x, a_o0); a_o1 = fdot2(wo1z[0], qz.x, a_o1);
      a_o0 = fdot2(wo0z[1], qz.y, a_o0); a_o1 = fdot2(wo1z[1], qz.y, a_o1);
      a_o0 = fdot2(wo0z[2], qz.z, a_o0); a_o1 = fdot2(wo1z[2], qz.z, a_o1);
      a_o0 = fdot2(wo0z[3], qz.w, a_o0); a_o1 = fdot2(wo1z[3], qz.w, a_o1);
    }
    a_pm = red8(a_pm); a_pl = red8(a_pl); a_o0 = red8(a_o0); a_o1 = red8(a_o1);
    if (c8 == 0) {
      s_act[144 + row8] = (_Float16)fmaxf(a_pm + s_bias[128 + row8], 0.f);
      s_act[216 + row8] = (_Float16)fmaxf(a_pl + s_bias[192 + row8], 0.f);
      float s0 = 1.f / (1.f + __expf(-(a_o0 + s_bias[832 + row8])));
      float s1 = 1.f / (1.f + __expf(-(a_o1 + s_bias[896 + row8])));
      storeOut(out, g * 128 + row8, s0, isbf);
      storeOut(out, g * 128 + 64 + row8, s1, isbf);
    }
    barrier_lds();

    // ---- P2': p L2 (gid<64: pmu row, gid>=64: plv row), 4 lanes/dot ----
    {
      const uint32_t* ab = s_actu + (mp ? 108 : 72) + c4 * 8;
      uint4 a0 = *(const uint4*)ab, a1 = *(const uint4*)(ab + 4);
      float v0 = 0.f, v1 = 0.f;
      v0 = fdot2(pw[0], a0.x, v0); v1 = fdot2(pw[4], a1.x, v1);
      v0 = fdot2(pw[1], a0.y, v0); v1 = fdot2(pw[5], a1.y, v1);
      v0 = fdot2(pw[2], a0.z, v0); v1 = fdot2(pw[6], a1.z, v1);
      v0 = fdot2(pw[3], a0.w, v0); v1 = fdot2(pw[7], a1.w, v1);
      float v = red4(v0 + v1);
      if (c4 == 0) {
        v += s_bias[(mp ? 512 : 448) + rr];
        storeOut(out, (mp ? OFF_PLV : OFF_PMU) + g * 64 + rr, v, isbf);
      }
    }
    barrier_lds();
  }
}

extern "C" void kernel_launch(void* const* d_in, const int* in_sizes, int n_in,
                              void* d_out, int out_size, void* d_ws, size_t ws_size,
                              hipStream_t stream) {
  (void)in_sizes; (void)n_in; (void)out_size; (void)ws_size;
  PrepArgs a;
  a.W[0]  = d_in[11]; // Wqm1 [50,384]
  a.W[1]  = d_in[15]; // Wql1 [50,384]
  a.W[2]  = d_in[3];  // Wpm1 [50,256]
  a.W[3]  = d_in[7];  // Wpl1 [50,256]
  a.W[4]  = d_in[19]; // Wh1  [50,448]
  a.W[5]  = d_in[23]; // Wo   [128,320]
  a.W[6]  = d_in[13]; // Wqm2 [64,50]
  a.W[7]  = d_in[17]; // Wql2 [64,50]
  a.W[8]  = d_in[5];  // Wpm2 [64,50]
  a.W[9]  = d_in[9];  // Wpl2 [64,50]
  a.W[10] = d_in[21]; // Wh2  [256,50]
  a.B[0]  = d_in[12]; // bqm1
  a.B[1]  = d_in[16]; // bql1
  a.B[2]  = d_in[4];  // bpm1
  a.B[3]  = d_in[8];  // bpl1
  a.B[4]  = d_in[20]; // bh1
  a.B[5]  = d_in[14]; // bqm2
  a.B[6]  = d_in[18]; // bql2
  a.B[7]  = d_in[6];  // bpm2
  a.B[8]  = d_in[10]; // bpl2
  a.B[9]  = d_in[22]; // bh2
  a.B[10] = d_in[24]; // bo
  a.xw    = (const uint32_t*)d_in[0];

  uint32_t* ws = (uint32_t*)d_ws;
  vrnn_prep<<<dim3((N_JOBS + 255) / 256), dim3(256), 0, stream>>>(a, ws);
  vrnn_main<<<dim3(256), dim3(512), 0, stream>>>(d_in[0], d_in[1], d_in[2], ws, d_out);
  vrnn_post<<<dim3(2048), dim3(512), 0, stream>>>(d_in[0], d_in[2], ws, d_out);
}

// Round 6
// 1426.747 us; speedup vs baseline: 1.3456x; 1.0622x over previous
//
#include <hip/hip_runtime.h>
#include <stdint.h>

// ============================================================================
// StochasticLSTMPredictor VRNN scan. B=256,T=512,I=128,H=256,L=64,HPR=50
// R9: FUSED single-pass kernel. R8 counters: main 845us @ 32% VALUBusy
// (~2700 stall cyc/t in the barrier gaps), post ~650us despite ~100us floor
// (1 bt per 512-thread block-iter = too little work per barrier). The p-path
// (pm/pl MLPs) + Wo/x_hat work (~73k MACs/t) fits inside main's stall slack,
// and h_t/z_t are live in LDS at P3 of step t. So fuse:
//  - P3 += pm/pl L1 dots + full Wo dots + sigmoid + x_hat store (h_t,z_t live)
//  - P4 += p-L2 (pmu/plv) using acts written in P3
//  - all weights register-resident (188 u32 pinned, AGPR-backed ok);
//    no parking, no post kernel, no park traffic.
// Phase structure = verified R3 shape; per-phase code reused from R8 kernels.
// ============================================================================

typedef _Float16 f16x2 __attribute__((ext_vector_type(2)));

__device__ __forceinline__ float bf2f(uint16_t u) {
  union { uint32_t u; float f; } c; c.u = ((uint32_t)u) << 16; return c.f;
}
__device__ __forceinline__ uint16_t f2bf(float f) {
  union { float f; uint32_t u; } c; c.f = f;
  uint32_t u = c.u;
  uint32_t r = (u + 0x7FFFu + ((u >> 16) & 1u)) >> 16;
  return (uint16_t)r;
}
__device__ __forceinline__ uint32_t packh2(float a, float b) {
  union { f16x2 h; uint32_t u; } c;
  c.h.x = (_Float16)a; c.h.y = (_Float16)b; return c.u;
}
__device__ __forceinline__ float fdot2(uint32_t a, uint32_t b, float c) {
  union { uint32_t u; f16x2 h; } ua, ub; ua.u = a; ub.u = b;
#if __has_builtin(__builtin_amdgcn_fdot2)
  return __builtin_amdgcn_fdot2(ua.h, ub.h, c, false);
#else
  return c + (float)ua.h.x * (float)ub.h.x + (float)ua.h.y * (float)ub.h.y;
#endif
}

// keep a value in a VGPR; forbids load-sinking/remat of its producer
__device__ __forceinline__ void pin(uint32_t& x) { asm volatile("" : "+v"(x)); }

// ---- DPP butterfly reduction (VALU pipe, no LDS) ----
template <int CTRL>
__device__ __forceinline__ float dpp_mov(float x) {
#if __has_builtin(__builtin_amdgcn_update_dpp)
  union { float f; int i; } a, b;
  a.f = x;
  b.i = __builtin_amdgcn_update_dpp(0, a.i, CTRL, 0xF, 0xF, true);
  return b.f;
#else
  return __shfl_xor(x, (CTRL == 0xB1) ? 1 : (CTRL == 0x4E) ? 2 : 4);
#endif
}
__device__ __forceinline__ float red2(float x) {           // sum over lane pairs
  return x + dpp_mov<0xB1>(x);
}
__device__ __forceinline__ float red4(float x) {           // sum over quads
  x += dpp_mov<0xB1>(x); x += dpp_mov<0x4E>(x); return x;
}
__device__ __forceinline__ float red8(float x) {           // sum over 8 lanes
  x += dpp_mov<0xB1>(x); x += dpp_mov<0x4E>(x); x += dpp_mov<0x141>(x); return x;
}

// LDS-only barrier: no vmcnt(0) drain (global stores/prefetches stay in flight)
__device__ __forceinline__ void barrier_lds() {
  asm volatile("s_waitcnt lgkmcnt(0)\n\ts_barrier" ::: "memory");
}

// dtype sniff (harness test is bf16; reference f32 — support both)
__device__ __forceinline__ int sniff_bf16(const uint32_t* xw) {
  int cnt = 0;
#pragma unroll
  for (int i = 0; i < 64; ++i) {
    uint32_t e = (xw[i] >> 7) & 0xFFu;
    cnt += (e >= 0x70u && e <= 0x7Fu) ? 1 : 0;
  }
  return cnt >= 32;
}
__device__ __forceinline__ float loadIn(const void* p, size_t i, int isbf) {
  return isbf ? bf2f(((const uint16_t*)p)[i]) : ((const float*)p)[i];
}
__device__ __forceinline__ void storeOut(void* p, size_t i, float v, int isbf) {
  if (isbf) ((uint16_t*)p)[i] = f2bf(v);
  else      ((float*)p)[i] = v;
}

// ws layout (uint32 units):
// [0, 75776)          : 148 pairs x 512 threads, SoA [pair][tid], f16x2
// [75776, 94208)      : W2 image: qm2@0 ql2@2304 pm2@4608 pl2@6912 (64 rows x
//                       stride36), wh2@9216 (256 rows x stride36)
// [94208, 95168)      : biases f32: [0:320) L1 5x64 | [320:576) L2 4x64
//                       | [576:832) bh2 | [832:960) bo
#define WS_W2   75776
#define WS_BIAS 94208
#define N_JOBS  95168

#define OFF_PMU 16777216u
#define OFF_PLV 25165824u
#define OFF_QMU 33554432u
#define OFF_QLV 41943040u

struct PrepArgs {
  const void* W[11]; // qm1 ql1 pm1 pl1 h1 wo qm2 ql2 pm2 pl2 h2
  const void* B[11]; // bqm1 bql1 bpm1 bpl1 bh1 bqm2 bql2 bpm2 bpl2 bh2 bo
  const uint32_t* xw;
};

__global__ void vrnn_prep(PrepArgs a, uint32_t* __restrict__ ws) {
  const int isbf = sniff_bf16(a.xw);
  int j = blockIdx.x * 256 + threadIdx.x;
  if (j < 75776) {
    int p = j >> 9, tid = j & 511;
    int t8 = tid >> 3, c8 = tid & 7;
    const void* W; int row, k, K; bool valid;
    if (p < 24)       { W = a.W[0]; row = t8; k = c8*48 + p*2;        K = 384; valid = row < 50; }
    else if (p < 48)  { W = a.W[1]; row = t8; k = c8*48 + (p-24)*2;   K = 384; valid = row < 50; }
    else if (p < 64)  { W = a.W[2]; row = t8; k = c8*32 + (p-48)*2;   K = 256; valid = row < 50; }
    else if (p < 80)  { W = a.W[3]; row = t8; k = c8*32 + (p-64)*2;   K = 256; valid = row < 50; }
    else if (p < 104) { W = a.W[4]; row = t8; k = c8*48 + (p-80)*2;   K = 448; valid = row < 50; }
    else if (p < 108) { W = a.W[4]; row = t8; k = 384 + c8*8 + (p-104)*2; K = 448; valid = row < 50; }
    else if (p < 124) { W = a.W[5]; row = t8;      k = c8*32 + (p-108)*2;     K = 320; valid = true; }
    else if (p < 128) { W = a.W[5]; row = t8;      k = 256 + c8*8 + (p-124)*2; K = 320; valid = true; }
    else if (p < 144) { W = a.W[5]; row = 64 + t8; k = c8*32 + (p-128)*2;     K = 320; valid = true; }
    else              { W = a.W[5]; row = 64 + t8; k = 256 + c8*8 + (p-144)*2; K = 320; valid = true; }
    float f0 = valid ? loadIn(W, (size_t)row * K + k, isbf)     : 0.f;
    float f1 = valid ? loadIn(W, (size_t)row * K + k + 1, isbf) : 0.f;
    ws[j] = packh2(f0, f1);
  } else if (j < WS_BIAS) {
    int q = j - WS_W2;
    const void* W; int r, kp;
    if (q < 9216) { int m = q / 2304, rem = q % 2304; r = rem / 36; kp = rem % 36; W = a.W[6 + m]; }
    else          { int rem = q - 9216;               r = rem / 36; kp = rem % 36; W = a.W[10]; }
    uint32_t v = 0;
    if (kp < 25) v = packh2(loadIn(W, r * 50 + kp * 2, isbf),
                            loadIn(W, r * 50 + kp * 2 + 1, isbf));
    ws[j] = v;
  } else if (j < N_JOBS) {
    int q = j - WS_BIAS; float v = 0.f;
    if (q < 320)      { int m = q >> 6, i = q & 63; if (i < 50) v = loadIn(a.B[m], i, isbf); }
    else if (q < 576) { int m = (q - 320) >> 6;     v = loadIn(a.B[5 + m], q & 63, isbf); }
    else if (q < 832) { v = loadIn(a.B[9],  q - 576, isbf); }
    else              { v = loadIn(a.B[10], q - 832, isbf); }
    ((float*)ws)[j] = v;
  }
}

// ======================= fused main scan (everything) =======================
__global__ __launch_bounds__(512)
__attribute__((amdgpu_waves_per_eu(2, 2)))
void vrnn_main(
    const void* __restrict__ x, const void* __restrict__ hidden,
    const void* __restrict__ noise, const uint32_t* __restrict__ ws,
    void* __restrict__ out)
{
  __shared__ float s_bias[960];
  __shared__ __align__(16) _Float16 s_v[448];    // [x(128)|h(256)|z(64)]
  __shared__ __align__(16) uint32_t s_actu[180]; // qm@0 ql@36 pm@72 pl@108 acth@144 (u32 idx)
  _Float16* s_act = (_Float16*)s_actu;

  const int tid = threadIdx.x;
  const int b = blockIdx.x;
  const int isbf = sniff_bf16((const uint32_t*)x);

  const int row8 = tid >> 3, c8 = tid & 7;
  const int i2 = tid >> 2, c4 = tid & 3;          // P2: q row; P4: p-L2 dot id
  const int rh = tid >> 1, ch = tid & 1;          // P4 h-update
  const int mp = (i2 >> 6) & 1, rr = i2 & 63;     // p-L2: 0-63 pmu, 64-127 plv

  // ---- register-resident weights (pinned; 188 u32 total) ----
  uint32_t wqm1[24], wql1[24], wh1a[24], wh1z[4];
#pragma unroll
  for (int i = 0; i < 24; ++i) { wqm1[i] = ws[(0   + i) * 512 + tid]; pin(wqm1[i]); }
#pragma unroll
  for (int i = 0; i < 24; ++i) { wql1[i] = ws[(24  + i) * 512 + tid]; pin(wql1[i]); }
#pragma unroll
  for (int i = 0; i < 24; ++i) { wh1a[i] = ws[(80  + i) * 512 + tid]; pin(wh1a[i]); }
#pragma unroll
  for (int i = 0; i < 4;  ++i) { wh1z[i] = ws[(104 + i) * 512 + tid]; pin(wh1z[i]); }
  uint32_t wpm1[16], wpl1[16], wo0h[16], wo0z[4], wo1h[16], wo1z[4];
#pragma unroll
  for (int i = 0; i < 16; ++i) { wpm1[i] = ws[(48  + i) * 512 + tid]; pin(wpm1[i]); }
#pragma unroll
  for (int i = 0; i < 16; ++i) { wpl1[i] = ws[(64  + i) * 512 + tid]; pin(wpl1[i]); }
#pragma unroll
  for (int i = 0; i < 16; ++i) { wo0h[i] = ws[(108 + i) * 512 + tid]; pin(wo0h[i]); }
#pragma unroll
  for (int i = 0; i < 4;  ++i) { wo0z[i] = ws[(124 + i) * 512 + tid]; pin(wo0z[i]); }
#pragma unroll
  for (int i = 0; i < 16; ++i) { wo1h[i] = ws[(128 + i) * 512 + tid]; pin(wo1h[i]); }
#pragma unroll
  for (int i = 0; i < 4;  ++i) { wo1z[i] = ws[(144 + i) * 512 + tid]; pin(wo1z[i]); }

  const int r2 = i2 & 63;                          // q-L2 row (tid<256 active)
  uint32_t q2wm[8], q2wl[8];
#pragma unroll
  for (int j = 0; j < 8; ++j) { q2wm[j] = ws[WS_W2 + r2*36 + c4*8 + j];        pin(q2wm[j]); }
#pragma unroll
  for (int j = 0; j < 8; ++j) { q2wl[j] = ws[WS_W2 + 2304 + r2*36 + c4*8 + j]; pin(q2wl[j]); }
  uint32_t p4w[16];
#pragma unroll
  for (int j = 0; j < 16; ++j) { p4w[j] = ws[WS_W2 + 9216 + rh*36 + ch*16 + j]; pin(p4w[j]); }
  uint32_t pw[8];
#pragma unroll
  for (int j = 0; j < 8; ++j) { pw[j] = ws[WS_W2 + (mp ? 6912 : 4608) + rr*36 + c4*8 + j]; pin(pw[j]); }

  {
    const float* wsf = (const float*)(ws + WS_BIAS);
    for (int i = tid; i < 960; i += 512) s_bias[i] = wsf[i];
  }

  if (tid < 128)      s_v[tid] = (_Float16)loadIn(x, (size_t)b * 65536 + tid, isbf);
  else if (tid < 384) s_v[tid] = (_Float16)loadIn(hidden, (size_t)b * 256 + (tid - 128), isbf);
  else if (tid < 448) s_v[tid] = (_Float16)0.f;

  const uint4* v4 = (const uint4*)s_v;

  float eps_r = 0.f;
  if (c4 == 0 && i2 < 64) eps_r = loadIn(noise, (size_t)b * 32768 + i2, isbf);
  float xnext = 0.f;

  __syncthreads();

#pragma unroll 1
  for (int t = 0; t < 512; ++t) {
    const size_t bt = (size_t)b * 512 + t;
    // prefetch x_{t+1} (committed to s_v in P4)
    if (tid >= 384) {
      int tn = (t < 511) ? t + 1 : 511;
      xnext = loadIn(x, ((size_t)b * 512 + tn) * 128 + (tid - 384), isbf);
    }

    // ---- P1: q-path L1 + Wh1 (x,h)-part; 8 lanes/row ----
    float a_qm = 0.f, a_ql = 0.f, a_hx = 0.f;
    {
      const int g = c8 * 6;                        // xh = v[0:384]
#pragma unroll
      for (int i = 0; i < 6; ++i) {
        uint4 q = v4[g + i];
        a_qm = fdot2(wqm1[4*i+0], q.x, a_qm); a_ql = fdot2(wql1[4*i+0], q.x, a_ql); a_hx = fdot2(wh1a[4*i+0], q.x, a_hx);
        a_qm = fdot2(wqm1[4*i+1], q.y, a_qm); a_ql = fdot2(wql1[4*i+1], q.y, a_ql); a_hx = fdot2(wh1a[4*i+1], q.y, a_hx);
        a_qm = fdot2(wqm1[4*i+2], q.z, a_qm); a_ql = fdot2(wql1[4*i+2], q.z, a_ql); a_hx = fdot2(wh1a[4*i+2], q.z, a_hx);
        a_qm = fdot2(wqm1[4*i+3], q.w, a_qm); a_ql = fdot2(wql1[4*i+3], q.w, a_ql); a_hx = fdot2(wh1a[4*i+3], q.w, a_hx);
      }
    }
    a_qm = red8(a_qm); a_ql = red8(a_ql);
    if (c8 == 0) {
      s_act[row8]      = (_Float16)fmaxf(a_qm + s_bias[row8],      0.f);
      s_act[72 + row8] = (_Float16)fmaxf(a_ql + s_bias[64 + row8], 0.f);
    }
    barrier_lds();

    // ---- P2: q L2 (mu & lv per row) + z; waves 0-3 only ----
    if (tid < 256) {
      uint4 am0 = *(const uint4*)(s_actu + c4*8),      am1 = *(const uint4*)(s_actu + c4*8 + 4);
      uint4 al0 = *(const uint4*)(s_actu + 36 + c4*8), al1 = *(const uint4*)(s_actu + 36 + c4*8 + 4);
      float mu0 = 0.f, mu1 = 0.f, lv0 = 0.f, lv1 = 0.f;
      mu0 = fdot2(q2wm[0], am0.x, mu0); lv0 = fdot2(q2wl[0], al0.x, lv0);
      mu1 = fdot2(q2wm[4], am1.x, mu1); lv1 = fdot2(q2wl[4], al1.x, lv1);
      mu0 = fdot2(q2wm[1], am0.y, mu0); lv0 = fdot2(q2wl[1], al0.y, lv0);
      mu1 = fdot2(q2wm[5], am1.y, mu1); lv1 = fdot2(q2wl[5], al1.y, lv1);
      mu0 = fdot2(q2wm[2], am0.z, mu0); lv0 = fdot2(q2wl[2], al0.z, lv0);
      mu1 = fdot2(q2wm[6], am1.z, mu1); lv1 = fdot2(q2wl[6], al1.z, lv1);
      mu0 = fdot2(q2wm[3], am0.w, mu0); lv0 = fdot2(q2wl[3], al0.w, lv0);
      mu1 = fdot2(q2wm[7], am1.w, mu1); lv1 = fdot2(q2wl[7], al1.w, lv1);
      float mu = red4(mu0 + mu1);
      float lv = red4(lv0 + lv1);
      if (c4 == 0) {
        mu += s_bias[320 + r2];
        lv += s_bias[384 + r2];
        storeOut(out, OFF_QMU + bt * 64 + r2, mu, isbf);
        storeOut(out, OFF_QLV + bt * 64 + r2, lv, isbf);
        float z = mu + __expf(0.5f * lv) * eps_r;
        s_v[384 + r2] = (_Float16)z;
        int tn = (t < 511) ? t + 1 : 511;
        eps_r = loadIn(noise, ((size_t)b * 512 + tn) * 64 + r2, isbf);
      }
    }
    barrier_lds();

    // ---- P3: Wh1 z-part + p-path L1 + full Wo + x_hat (h_t, z_t live) ----
    {
      const int gg = 16 + c8 * 4;                  // h = v[128:384]
      uint4 h0 = v4[gg], h1 = v4[gg + 1], h2 = v4[gg + 2], h3 = v4[gg + 3];
      uint4 qz = v4[48 + c8];                      // z = v[384:448)
      float ah = a_hx;
      ah = fdot2(wh1z[0], qz.x, ah);
      ah = fdot2(wh1z[1], qz.y, ah);
      ah = fdot2(wh1z[2], qz.z, ah);
      ah = fdot2(wh1z[3], qz.w, ah);
      float a_pm = 0.f, a_pl = 0.f, a_o0 = 0.f, a_o1 = 0.f;
      a_pm = fdot2(wpm1[0],  h0.x, a_pm); a_pl = fdot2(wpl1[0],  h0.x, a_pl);
      a_o0 = fdot2(wo0h[0],  h0.x, a_o0); a_o1 = fdot2(wo1h[0],  h0.x, a_o1);
      a_pm = fdot2(wpm1[1],  h0.y, a_pm); a_pl = fdot2(wpl1[1],  h0.y, a_pl);
      a_o0 = fdot2(wo0h[1],  h0.y, a_o0); a_o1 = fdot2(wo1h[1],  h0.y, a_o1);
      a_pm = fdot2(wpm1[2],  h0.z, a_pm); a_pl = fdot2(wpl1[2],  h0.z, a_pl);
      a_o0 = fdot2(wo0h[2],  h0.z, a_o0); a_o1 = fdot2(wo1h[2],  h0.z, a_o1);
      a_pm = fdot2(wpm1[3],  h0.w, a_pm); a_pl = fdot2(wpl1[3],  h0.w, a_pl);
      a_o0 = fdot2(wo0h[3],  h0.w, a_o0); a_o1 = fdot2(wo1h[3],  h0.w, a_o1);
      a_pm = fdot2(wpm1[4],  h1.x, a_pm); a_pl = fdot2(wpl1[4],  h1.x, a_pl);
      a_o0 = fdot2(wo0h[4],  h1.x, a_o0); a_o1 = fdot2(wo1h[4],  h1.x, a_o1);
      a_pm = fdot2(wpm1[5],  h1.y, a_pm); a_pl = fdot2(wpl1[5],  h1.y, a_pl);
      a_o0 = fdot2(wo0h[5],  h1.y, a_o0); a_o1 = fdot2(wo1h[5],  h1.y, a_o1);
      a_pm = fdot2(wpm1[6],  h1.z, a_pm); a_pl = fdot2(wpl1[6],  h1.z, a_pl);
      a_o0 = fdot2(wo0h[6],  h1.z, a_o0); a_o1 = fdot2(wo1h[6],  h1.z, a_o1);
      a_pm = fdot2(wpm1[7],  h1.w, a_pm); a_pl = fdot2(wpl1[7],  h1.w, a_pl);
      a_o0 = fdot2(wo0h[7],  h1.w, a_o0); a_o1 = fdot2(wo1h[7],  h1.w, a_o1);
      a_pm = fdot2(wpm1[8],  h2.x, a_pm); a_pl = fdot2(wpl1[8],  h2.x, a_pl);
      a_o0 = fdot2(wo0h[8],  h2.x, a_o0); a_o1 = fdot2(wo1h[8],  h2.x, a_o1);
      a_pm = fdot2(wpm1[9],  h2.y, a_pm); a_pl = fdot2(wpl1[9],  h2.y, a_pl);
      a_o0 = fdot2(wo0h[9],  h2.y, a_o0); a_o1 = fdot2(wo1h[9],  h2.y, a_o1);
      a_pm = fdot2(wpm1[10], h2.z, a_pm); a_pl = fdot2(wpl1[10], h2.z, a_pl);
      a_o0 = fdot2(wo0h[10], h2.z, a_o0); a_o1 = fdot2(wo1h[10], h2.z, a_o1);
      a_pm = fdot2(wpm1[11], h2.w, a_pm); a_pl = fdot2(wpl1[11], h2.w, a_pl);
      a_o0 = fdot2(wo0h[11], h2.w, a_o0); a_o1 = fdot2(wo1h[11], h2.w, a_o1);
      a_pm = fdot2(wpm1[12], h3.x, a_pm); a_pl = fdot2(wpl1[12], h3.x, a_pl);
      a_o0 = fdot2(wo0h[12], h3.x, a_o0); a_o1 = fdot2(wo1h[12], h3.x, a_o1);
      a_pm = fdot2(wpm1[13], h3.y, a_pm); a_pl = fdot2(wpl1[13], h3.y, a_pl);
      a_o0 = fdot2(wo0h[13], h3.y, a_o0); a_o1 = fdot2(wo1h[13], h3.y, a_o1);
      a_pm = fdot2(wpm1[14], h3.z, a_pm); a_pl = fdot2(wpl1[14], h3.z, a_pl);
      a_o0 = fdot2(wo0h[14], h3.z, a_o0); a_o1 = fdot2(wo1h[14], h3.z, a_o1);
      a_pm = fdot2(wpm1[15], h3.w, a_pm); a_pl = fdot2(wpl1[15], h3.w, a_pl);
      a_o0 = fdot2(wo0h[15], h3.w, a_o0); a_o1 = fdot2(wo1h[15], h3.w, a_o1);
      // Wo z-part
      a_o0 = fdot2(wo0z[0], qz.x, a_o0); a_o1 = fdot2(wo1z[0], qz.x, a_o1);
      a_o0 = fdot2(wo0z[1], qz.y, a_o0); a_o1 = fdot2(wo1z[1], qz.y, a_o1);
      a_o0 = fdot2(wo0z[2], qz.z, a_o0); a_o1 = fdot2(wo1z[2], qz.z, a_o1);
      a_o0 = fdot2(wo0z[3], qz.w, a_o0); a_o1 = fdot2(wo1z[3], qz.w, a_o1);
      ah = red8(ah); a_pm = red8(a_pm); a_pl = red8(a_pl);
      a_o0 = red8(a_o0); a_o1 = red8(a_o1);
      if (c8 == 0) {
        s_act[288 + row8] = (_Float16)fmaxf(ah   + s_bias[256 + row8], 0.f);
        s_act[144 + row8] = (_Float16)fmaxf(a_pm + s_bias[128 + row8], 0.f);
        s_act[216 + row8] = (_Float16)fmaxf(a_pl + s_bias[192 + row8], 0.f);
        float s0 = 1.f / (1.f + __expf(-(a_o0 + s_bias[832 + row8])));
        float s1 = 1.f / (1.f + __expf(-(a_o1 + s_bias[896 + row8])));
        storeOut(out, bt * 128 + row8, s0, isbf);
        storeOut(out, bt * 128 + 64 + row8, s1, isbf);
      }
    }
    barrier_lds();

    // ---- P4: h-update (2 lanes/row) + p-L2 (pmu/plv); commit x_{t+1} ----
    {
      const uint32_t* ap = s_actu + 144 + ch * 16;
      uint4 a0 = *(const uint4*)ap,        a1 = *(const uint4*)(ap + 4);
      uint4 a2 = *(const uint4*)(ap + 8),  a3 = *(const uint4*)(ap + 12);
      float h0 = 0.f, h1 = 0.f;
      h0 = fdot2(p4w[0],  a0.x, h0); h1 = fdot2(p4w[8],  a2.x, h1);
      h0 = fdot2(p4w[1],  a0.y, h0); h1 = fdot2(p4w[9],  a2.y, h1);
      h0 = fdot2(p4w[2],  a0.z, h0); h1 = fdot2(p4w[10], a2.z, h1);
      h0 = fdot2(p4w[3],  a0.w, h0); h1 = fdot2(p4w[11], a2.w, h1);
      h0 = fdot2(p4w[4],  a1.x, h0); h1 = fdot2(p4w[12], a3.x, h1);
      h0 = fdot2(p4w[5],  a1.y, h0); h1 = fdot2(p4w[13], a3.y, h1);
      h0 = fdot2(p4w[6],  a1.z, h0); h1 = fdot2(p4w[14], a3.z, h1);
      h0 = fdot2(p4w[7],  a1.w, h0); h1 = fdot2(p4w[15], a3.w, h1);
      float hh = red2(h0 + h1);

      // p-L2: i2 in 0..127 -> pmu/plv row rr, 4 lanes/dot
      const uint32_t* ab = s_actu + (mp ? 108 : 72) + c4 * 8;
      uint4 b0 = *(const uint4*)ab, b1 = *(const uint4*)(ab + 4);
      float v0 = 0.f, v1 = 0.f;
      v0 = fdot2(pw[0], b0.x, v0); v1 = fdot2(pw[4], b1.x, v1);
      v0 = fdot2(pw[1], b0.y, v0); v1 = fdot2(pw[5], b1.y, v1);
      v0 = fdot2(pw[2], b0.z, v0); v1 = fdot2(pw[6], b1.z, v1);
      v0 = fdot2(pw[3], b0.w, v0); v1 = fdot2(pw[7], b1.w, v1);
      float pv = red4(v0 + v1);

      if (ch == 0) s_v[128 + rh] = (_Float16)(hh + s_bias[576 + rh]);
      if (c4 == 0 && i2 < 128) {
        pv += s_bias[(mp ? 512 : 448) + rr];
        storeOut(out, (mp ? OFF_PLV : OFF_PMU) + bt * 64 + rr, pv, isbf);
      }
    }
    if (tid >= 384) s_v[tid - 384] = (_Float16)xnext;
    barrier_lds();
  }
}

extern "C" void kernel_launch(void* const* d_in, const int* in_sizes, int n_in,
                              void* d_out, int out_size, void* d_ws, size_t ws_size,
                              hipStream_t stream) {
  (void)in_sizes; (void)n_in; (void)out_size; (void)ws_size;
  PrepArgs a;
  a.W[0]  = d_in[11]; // Wqm1 [50,384]
  a.W[1]  = d_in[15]; // Wql1 [50,384]
  a.W[2]  = d_in[3];  // Wpm1 [50,256]
  a.W[3]  = d_in[7];  // Wpl1 [50,256]
  a.W[4]  = d_in[19]; // Wh1  [50,448]
  a.W[5]  = d_in[23]; // Wo   [128,320]
  a.W[6]  = d_in[13]; // Wqm2 [64,50]
  a.W[7]  = d_in[17]; // Wql2 [64,50]
  a.W[8]  = d_in[5];  // Wpm2 [64,50]
  a.W[9]  = d_in[9];  // Wpl2 [64,50]
  a.W[10] = d_in[21]; // Wh2  [256,50]
  a.B[0]  = d_in[12]; // bqm1
  a.B[1]  = d_in[16]; // bql1
  a.B[2]  = d_in[4];  // bpm1
  a.B[3]  = d_in[8];  // bpl1
  a.B[4]  = d_in[20]; // bh1
  a.B[5]  = d_in[14]; // bqm2
  a.B[6]  = d_in[18]; // bql2
  a.B[7]  = d_in[6];  // bpm2
  a.B[8]  = d_in[10]; // bpl2
  a.B[9]  = d_in[22]; // bh2
  a.B[10] = d_in[24]; // bo
  a.xw    = (const uint32_t*)d_in[0];

  uint32_t* ws = (uint32_t*)d_ws;
  vrnn_prep<<<dim3((N_JOBS + 255) / 256), dim3(256), 0, stream>>>(a, ws);
  vrnn_main<<<dim3(256), dim3(512), 0, stream>>>(d_in[0], d_in[1], d_in[2], ws, d_out);
}